// Round 3
// baseline (79.841 us; speedup 1.0000x reference)
//
#include <hip/hip_runtime.h>
#include <hip/hip_bf16.h>
#include <math.h>

#define N_HEAD 16
#define N_EMBD 1024
#define HEADD  64
#define BANDW  64          // keys j in [i-64, i] visible
#define BB     2
#define TT     2048

typedef __attribute__((ext_vector_type(8))) short bf16x8;
typedef __attribute__((ext_vector_type(4))) float f32x4;

__device__ __forceinline__ ushort f2b(float f) {
    __hip_bfloat16 h = __float2bfloat16(f);
    union { __hip_bfloat16 h; ushort u; } cv; cv.h = h; return cv.u;
}
__device__ __forceinline__ float b2f(ushort u) { return __uint_as_float(((unsigned)u) << 16); }

// async global->LDS, 16B per lane; LDS dest = wave-uniform base (+lane*16 implicit)
#define GLOAD16(gp, lp) \
    __builtin_amdgcn_global_load_lds((const __attribute__((address_space(1))) void*)(gp), \
                                     (__attribute__((address_space(3))) void*)(lp), 16, 0, 0)

// ---------------- fused prep: x->bf16 + both weight transposes ----------------
__global__ __launch_bounds__(256) void k_prep(
    const float* __restrict__ x, ushort* __restrict__ xb,
    const float* __restrict__ Wqkv, ushort* __restrict__ wqkvT,
    const float* __restrict__ Wproj, ushort* __restrict__ wprojT)
{
    __shared__ float tile[32][33];
    int bid = blockIdx.x;
    int t = threadIdx.x;
    if (bid < 4096) {                       // x -> bf16 (4M floats, float4/thread)
        int i = bid * 256 + t;
        float4 v = reinterpret_cast<const float4*>(x)[i];
        ushort4 o;
        o.x = f2b(v.x); o.y = f2b(v.y); o.z = f2b(v.z); o.w = f2b(v.w);
        reinterpret_cast<ushort4*>(xb)[i] = o;
        return;
    }
    const float* in; ushort* out; int R, C, bx, by;
    if (bid < 4096 + 3072) {                // Wqkv [1024][3072] -> [3072][1024]
        int b2 = bid - 4096;
        in = Wqkv; out = wqkvT; R = 1024; C = 3072;
        bx = b2 % 96; by = b2 / 96;
    } else {                                // Wproj [1024][1024] -> transposed
        int b3 = bid - 7168;
        in = Wproj; out = wprojT; R = 1024; C = 1024;
        bx = b3 & 31; by = b3 >> 5;
    }
    int tx = t & 31, ty = t >> 5;
    int c0 = bx * 32, r0 = by * 32;
    for (int rr = ty; rr < 32; rr += 8)
        tile[rr][tx] = in[(size_t)(r0 + rr) * C + (c0 + tx)];
    __syncthreads();
    for (int cc = ty; cc < 32; cc += 8)
        out[(size_t)(c0 + cc) * R + (r0 + tx)] = f2b(tile[tx][cc]);
}

// ===== GEMM1: 256x256 tile, BK=32, TRIPLE-buffered 2-phase/K-tile schedule =====
// T3+T4+T5 derived schedule: stage tile t+2 during tile t (A in ph0, B in ph1),
// one counted s_waitcnt vmcnt(4) per K-tile (confirms tile t+1; never drains to
// 0 in steady state), 2 barriers/phase, setprio(1) around each 16-MFMA cluster.
// 8 waves (2Mx4N), per-wave 128x64 output, acc[8][4] = 128 VGPR. 96 KB LDS,
// 1 block/CU, grid 16x12=192 (XCD-bijective swizzle).
template <bool OUT_BF16>
__global__ __launch_bounds__(512, 2) void k_gemm1(
    const ushort* __restrict__ A, const ushort* __restrict__ BT,
    const float* __restrict__ bias, void* __restrict__ Cout,
    int M, int N, int K)
{
    __shared__ __align__(16) char lds[3 * 32768];   // 3 bufs x (A 16K | B 16K)
    const int K2 = K * 2;
    int tid = threadIdx.x, lane = tid & 63, w = tid >> 6;
    int wm = w >> 2, wn = w & 3;
    int lr = lane & 15, kg = lane >> 4;

    int nbx = N >> 8;                 // 256-col tiles (=12)
    int cpx = gridDim.x >> 3;
    int wg = blockIdx.x;
    int wgid = (wg & 7) * cpx + (wg >> 3);
    int bx = wgid % nbx, by = wgid / nbx;
    int row0 = by * 256, col0 = bx * 256;

    // stage source offsets (identical for A and B regions): 16KB region =
    // 256 rows x 64B; rot4 of 16B blocks by (r>>1)&3 within each row.
    size_t sS0, sS1;
    {
        int o = w * 1024 + lane * 16;
        int r = o >> 6;
        int c = (((o >> 4) & 3) - ((r >> 1) & 3)) & 3;
        sS0 = (size_t)r * K2 + (size_t)c * 16;
        o += 8192; r = o >> 6;
        c = (((o >> 4) & 3) - ((r >> 1) & 3)) & 3;
        sS1 = (size_t)r * K2 + (size_t)c * 16;
    }
    const char* gA = (const char*)A  + (size_t)row0 * K2;
    const char* gB = (const char*)BT + (size_t)col0 * K2;

    int offA[8], offB[4];
#pragma unroll
    for (int m = 0; m < 8; ++m) {
        int rr = wm * 128 + m * 16 + lr;
        offA[m] = rr * 64 + ((kg + ((rr >> 1) & 3)) & 3) * 16;
    }
#pragma unroll
    for (int n = 0; n < 4; ++n) {
        int rr = wn * 64 + n * 16 + lr;
        offB[n] = 16384 + rr * 64 + ((kg + ((rr >> 1) & 3)) & 3) * 16;
    }

    f32x4 acc[8][4];
#pragma unroll
    for (int i = 0; i < 8; ++i)
#pragma unroll
        for (int j = 0; j < 4; ++j) { f32x4 z = {0.f, 0.f, 0.f, 0.f}; acc[i][j] = z; }

#define STG_A(BI, TI) do { \
        char* _db = lds + (BI) * 32768; \
        const char* _g = gA + (size_t)(TI) * 64; \
        GLOAD16(_g + sS0, _db + w * 1024); \
        GLOAD16(_g + sS1, _db + 8192 + w * 1024); \
    } while (0)
#define STG_B(BI, TI) do { \
        char* _db = lds + (BI) * 32768 + 16384; \
        const char* _g = gB + (size_t)(TI) * 64; \
        GLOAD16(_g + sS0, _db + w * 1024); \
        GLOAD16(_g + sS1, _db + 8192 + w * 1024); \
    } while (0)

    int nt = K >> 5;                  // 32 K-tiles of 32
    // prologue: tiles 0 and 1 in flight; confirm tile 0 (wait-to-4)
    STG_A(0, 0); STG_B(0, 0); STG_A(1, 1); STG_B(1, 1);
    asm volatile("s_waitcnt vmcnt(4)" ::: "memory");
    __builtin_amdgcn_s_barrier();

#pragma unroll 3
    for (int t = 0; t < nt; ++t) {
        const char* bufb = lds + (t % 3) * 32768;
        // ---------- phase 0: frags m0-3 x n0-3 ----------
        bf16x8 a[4], b[4];
#pragma unroll
        for (int m = 0; m < 4; ++m)
            a[m] = *(const bf16x8*)(bufb + offA[m]);
#pragma unroll
        for (int n = 0; n < 4; ++n)
            b[n] = *(const bf16x8*)(bufb + offB[n]);
        if (t + 2 < nt) STG_A((t + 2) % 3, t + 2);
        __builtin_amdgcn_s_barrier();
        asm volatile("s_waitcnt lgkmcnt(0)" ::: "memory");
        __builtin_amdgcn_sched_barrier(0);
        __builtin_amdgcn_s_setprio(1);
#pragma unroll
        for (int m = 0; m < 4; ++m)
#pragma unroll
            for (int n = 0; n < 4; ++n)
                acc[m][n] = __builtin_amdgcn_mfma_f32_16x16x32_bf16(
                    a[m], b[n], acc[m][n], 0, 0, 0);
        __builtin_amdgcn_s_setprio(0);
        __builtin_amdgcn_s_barrier();
        // ---------- phase 1: frags m4-7 x n0-3 (reuse b) ----------
        bf16x8 a2[4];
#pragma unroll
        for (int m = 0; m < 4; ++m)
            a2[m] = *(const bf16x8*)(bufb + offA[4 + m]);
        if (t + 2 < nt) {
            STG_B((t + 2) % 3, t + 2);
            asm volatile("s_waitcnt vmcnt(4)" ::: "memory");  // confirms tile t+1
        } else {
            asm volatile("s_waitcnt vmcnt(0)" ::: "memory");  // tail drain
        }
        __builtin_amdgcn_s_barrier();
        asm volatile("s_waitcnt lgkmcnt(0)" ::: "memory");
        __builtin_amdgcn_sched_barrier(0);
        __builtin_amdgcn_s_setprio(1);
#pragma unroll
        for (int m = 0; m < 4; ++m)
#pragma unroll
            for (int n = 0; n < 4; ++n)
                acc[4 + m][n] = __builtin_amdgcn_mfma_f32_16x16x32_bf16(
                    a2[m], b[n], acc[4 + m][n], 0, 0, 0);
        __builtin_amdgcn_s_setprio(0);
        __builtin_amdgcn_s_barrier();
    }
#undef STG_A
#undef STG_B

#pragma unroll
    for (int m = 0; m < 8; ++m) {
        int growb = row0 + wm * 128 + m * 16 + kg * 4;
#pragma unroll
        for (int n = 0; n < 4; ++n) {
            int gcol = col0 + wn * 64 + n * 16 + lr;
            float bv = bias ? bias[gcol] : 0.f;
#pragma unroll
            for (int e = 0; e < 4; ++e) {
                float val = acc[m][n][e] + bv;
                if (OUT_BF16)
                    ((ushort*)Cout)[(size_t)(growb + e) * N + gcol] = f2b(val);
                else
                    ((float*)Cout)[(size_t)(growb + e) * N + gcol] = val;
            }
        }
    }
}

// ====== 128x64 2-phase dbuf GEMM (GEMM2), 256 thr / 4 waves, 3 blocks/CU ======
template <bool OUT_BF16>
__global__ __launch_bounds__(256, 3) void k_gemm2(
    const ushort* __restrict__ A, const ushort* __restrict__ BT,
    const float* __restrict__ bias, void* __restrict__ Cout,
    int M, int N, int K)
{
    __shared__ __align__(16) char lds[2 * 24576];
    const int K2 = K * 2;
    int t = threadIdx.x, lane = t & 63, w = t >> 6;   // 4 waves
    int wm = w >> 1, wn = w & 1;                      // 2M x 2N wave grid
    int lr = lane & 15, kg = lane >> 4;

    int nbx = N >> 6;                                 // tiles of 64 cols
    int cpx = gridDim.x >> 3;
    int wg = blockIdx.x;
    int wgid = (wg & 7) * cpx + (wg >> 3);
    int bx = wgid % nbx, by = wgid / nbx;
    int row0 = by * 128, col0 = bx * 64;

    size_t sA[4], sB[2];
#pragma unroll
    for (int u = 0; u < 4; ++u) {
        int o = w * 4096 + u * 1024 + lane * 16;
        int r = o >> 7, c = ((o >> 4) - r) & 7;
        sA[u] = (size_t)r * K2 + c * 16;
    }
#pragma unroll
    for (int u = 0; u < 2; ++u) {
        int o = w * 2048 + u * 1024 + lane * 16;
        int r = o >> 7, c = ((o >> 4) - r) & 7;
        sB[u] = (size_t)r * K2 + c * 16;
    }
    const char* gA = (const char*)A  + (size_t)row0 * K2;
    const char* gB = (const char*)BT + (size_t)col0 * K2;

    int offA[4][2], offB[2][2];
#pragma unroll
    for (int m = 0; m < 4; ++m) {
        int rr = wm * 64 + m * 16 + lr;
#pragma unroll
        for (int ks = 0; ks < 2; ++ks)
            offA[m][ks] = rr * 128 + (((ks * 4 + kg) + rr) & 7) * 16;
    }
#pragma unroll
    for (int n = 0; n < 2; ++n) {
        int rr = wn * 32 + n * 16 + lr;
#pragma unroll
        for (int ks = 0; ks < 2; ++ks)
            offB[n][ks] = rr * 128 + (((ks * 4 + kg) + rr) & 7) * 16;
    }

    f32x4 acc[4][2];
#pragma unroll
    for (int i = 0; i < 4; ++i)
#pragma unroll
        for (int j = 0; j < 2; ++j) { f32x4 z = {0.f, 0.f, 0.f, 0.f}; acc[i][j] = z; }

#define STAGE2(BUF, TI) do { \
        char* _db = lds + (BUF) * 24576; \
        const char* _ga = gA + (size_t)(TI) * 128; \
        const char* _gb = gB + (size_t)(TI) * 128; \
        GLOAD16(_ga + sA[0], _db + w * 4096); \
        GLOAD16(_ga + sA[1], _db + w * 4096 + 1024); \
        GLOAD16(_ga + sA[2], _db + w * 4096 + 2048); \
        GLOAD16(_ga + sA[3], _db + w * 4096 + 3072); \
        GLOAD16(_gb + sB[0], _db + 16384 + w * 2048); \
        GLOAD16(_gb + sB[1], _db + 16384 + w * 2048 + 1024); \
    } while (0)

    STAGE2(0, 0);
    __syncthreads();

    int nt = K >> 6;
#pragma unroll 2
    for (int tt = 0; tt < nt; ++tt) {
        int cur = tt & 1;
        if (tt + 1 < nt) STAGE2(cur ^ 1, tt + 1);
        const char* bufb = lds + cur * 24576;
#pragma unroll
        for (int ks = 0; ks < 2; ++ks) {
            bf16x8 af[4], bfr[2];
#pragma unroll
            for (int m = 0; m < 4; ++m)
                af[m] = *(const bf16x8*)(bufb + offA[m][ks]);
#pragma unroll
            for (int n = 0; n < 2; ++n)
                bfr[n] = *(const bf16x8*)(bufb + 16384 + offB[n][ks]);
#pragma unroll
            for (int m = 0; m < 4; ++m)
#pragma unroll
                for (int n = 0; n < 2; ++n)
                    acc[m][n] = __builtin_amdgcn_mfma_f32_16x16x32_bf16(
                        af[m], bfr[n], acc[m][n], 0, 0, 0);
        }
        __syncthreads();
    }
#undef STAGE2

#pragma unroll
    for (int m = 0; m < 4; ++m) {
        int growb = row0 + wm * 64 + m * 16 + kg * 4;
#pragma unroll
        for (int n = 0; n < 2; ++n) {
            int gcol = col0 + wn * 32 + n * 16 + lr;
            float bv = bias ? bias[gcol] : 0.f;
#pragma unroll
            for (int e = 0; e < 4; ++e) {
                float val = acc[m][n][e] + bv;
                if (OUT_BF16)
                    ((ushort*)Cout)[(size_t)(growb + e) * N + gcol] = f2b(val);
                else
                    ((float*)Cout)[(size_t)(growb + e) * N + gcol] = val;
            }
        }
    }
}

// ---------------- banded causal attention, MFMA block-tiled ----------------
__global__ __launch_bounds__(256) void k_attn(const ushort* __restrict__ qkv,
                                              ushort* __restrict__ y) {
    __shared__ __align__(16) ushort Ks[128 * 64];   // 16 KB, rotated layout
    __shared__ ushort Vt[64][136];                  // [d][key]
    __shared__ ushort Ps[64][136];                  // [query][key]

    const int R3 = 3 * N_EMBD;
    int bid = blockIdx.x;
    int l  = (bid & 7) * 128 + (bid >> 3);   // bijective: grid 1024 = 8*128
    int qt = l & 31;
    int h  = (l >> 5) & (N_HEAD - 1);
    int b  = l >> 9;
    int i0 = qt * 64;
    int j0 = i0 - BANDW;
    int hc = h * HEADD;

    int t    = threadIdx.x;
    int lane = t & 63;
    int wq   = t >> 6;
    int lr   = lane & 15;
    int kg   = lane >> 4;

    // ---- K: async global_load_lds, rotated dest (each wave 4 KB) ----
    const ushort* kbase_g = qkv + (size_t)b * TT * R3 + N_EMBD + hc;
#pragma unroll
    for (int rnd = 0; rnd < 4; ++rnd) {
        int o = wq * 4096 + rnd * 1024 + lane * 16;  // byte offset in Ks
        int row  = o >> 7;
        int cblk = (((o >> 4) & 7) - row) & 7;       // inverse rotation
        int j = j0 + row; if (j < 0) j = 0;          // clamp; masked later
        GLOAD16((const char*)(kbase_g + (size_t)j * R3) + cblk * 16,
                (char*)Ks + wq * 4096 + rnd * 1024);
    }

    // ---- V: register staging + scalar transpose (round-8 proven) ----
    {
        int row  = t >> 1;            // 0..127 (key index in window)
        int part = t & 1;             // halves of the 64-wide d
        int j = j0 + row;
        if (j >= 0) {
            const ushort* vrow = qkv + (size_t)(b * TT + j) * R3 + 2 * N_EMBD + hc + part * 32;
#pragma unroll
            for (int c = 0; c < 4; ++c) {
                uint4 vv = reinterpret_cast<const uint4*>(vrow)[c];
                const ushort* pv = (const ushort*)&vv;
                int dbase = part * 32 + c * 8;
#pragma unroll
                for (int e = 0; e < 8; ++e)
                    Vt[dbase + e][row] = pv[e];
            }
        } else {
#pragma unroll
            for (int c = 0; c < 4; ++c) {
                int dbase = part * 32 + c * 8;
#pragma unroll
                for (int e = 0; e < 8; ++e)
                    Vt[dbase + e][row] = 0;
            }
        }
    }

    // ---- Q fragments direct from global ----
    const ushort* qbase = qkv + (size_t)(b * TT + i0 + wq * 16 + lr) * R3 + hc;
    bf16x8 aq0 = *reinterpret_cast<const bf16x8*>(qbase + kg * 8);
    bf16x8 aq1 = *reinterpret_cast<const bf16x8*>(qbase + 32 + kg * 8);

    __syncthreads();

    // ---- QK^T (rotated K reads; 2 lanes/slot per quarter-wave = conflict-free) ----
    f32x4 s[8];
#pragma unroll
    for (int nt = 0; nt < 8; ++nt) { f32x4 z = {0.f, 0.f, 0.f, 0.f}; s[nt] = z; }
#pragma unroll
    for (int nt = 0; nt < 8; ++nt) {
        int row = nt * 16 + lr;
        const char* kr = (const char*)Ks + row * 128;
        bf16x8 kb0 = *(const bf16x8*)(kr + (((kg)     + row) & 7) * 16);
        bf16x8 kb1 = *(const bf16x8*)(kr + (((4 + kg) + row) & 7) * 16);
        s[nt] = __builtin_amdgcn_mfma_f32_16x16x32_bf16(aq0, kb0, s[nt], 0, 0, 0);
        s[nt] = __builtin_amdgcn_mfma_f32_16x16x32_bf16(aq1, kb1, s[nt], 0, 0, 0);
    }

    // ---- mask + softmax (rows in (kg,e); reduce over lr via shfl_xor) ----
    float mx[4] = {-INFINITY, -INFINITY, -INFINITY, -INFINITY};
#pragma unroll
    for (int nt = 0; nt < 8; ++nt) {
        int kc = nt * 16 + lr;
#pragma unroll
        for (int e = 0; e < 4; ++e) {
            int qr = wq * 16 + kg * 4 + e;
            bool valid = (kc >= qr) && (kc <= qr + BANDW) && (j0 + kc >= 0);
            float v = s[nt][e] * 0.125f;
            s[nt][e] = valid ? v : -INFINITY;
            mx[e] = fmaxf(mx[e], s[nt][e]);
        }
    }
#pragma unroll
    for (int e = 0; e < 4; ++e) {
#pragma unroll
        for (int m = 1; m <= 8; m <<= 1)
            mx[e] = fmaxf(mx[e], __shfl_xor(mx[e], m, 64));
    }
    float sm[4] = {0.f, 0.f, 0.f, 0.f};
#pragma unroll
    for (int nt = 0; nt < 8; ++nt) {
        int kc = nt * 16 + lr;
#pragma unroll
        for (int e = 0; e < 4; ++e) {
            float p = __expf(s[nt][e] - mx[e]);
            sm[e] += p;
            Ps[wq * 16 + kg * 4 + e][kc] = f2b(p);
        }
    }
#pragma unroll
    for (int e = 0; e < 4; ++e) {
#pragma unroll
        for (int m = 1; m <= 8; m <<= 1)
            sm[e] += __shfl_xor(sm[e], m, 64);
    }
    // no barrier: each wave reads only its own Ps rows

    // ---- PV: y(16x64) = P(16x128) @ V(128x64), Vt is [d][key] ----
    f32x4 o[4];
#pragma unroll
    for (int vt = 0; vt < 4; ++vt) { f32x4 z = {0.f, 0.f, 0.f, 0.f}; o[vt] = z; }
#pragma unroll
    for (int ks = 0; ks < 4; ++ks) {
        bf16x8 pa = *reinterpret_cast<const bf16x8*>(&Ps[wq * 16 + lr][ks * 32 + kg * 8]);
#pragma unroll
        for (int vt = 0; vt < 4; ++vt) {
            bf16x8 vb = *reinterpret_cast<const bf16x8*>(&Vt[vt * 16 + lr][ks * 32 + kg * 8]);
            o[vt] = __builtin_amdgcn_mfma_f32_16x16x32_bf16(pa, vb, o[vt], 0, 0, 0);
        }
    }

    float inv[4];
#pragma unroll
    for (int e = 0; e < 4; ++e) inv[e] = 1.f / sm[e];

#pragma unroll
    for (int vt = 0; vt < 4; ++vt) {
#pragma unroll
        for (int e = 0; e < 4; ++e) {
            int qr = wq * 16 + kg * 4 + e;
            y[(size_t)(b * TT + i0 + qr) * N_EMBD + hc + vt * 16 + lr] =
                f2b(o[vt][e] * inv[e]);
        }
    }
}

// ---------------- launch ----------------
extern "C" void kernel_launch(void* const* d_in, const int* in_sizes, int n_in,
                              void* d_out, int out_size, void* d_ws, size_t ws_size,
                              hipStream_t stream) {
    const float* x     = (const float*)d_in[0];
    const float* Wqkv  = (const float*)d_in[1];
    const float* bqkv  = (const float*)d_in[2];
    const float* Wproj = (const float*)d_in[3];
    const float* bproj = (const float*)d_in[4];
    float* out = (float*)d_out;

    const int M  = BB * TT;     // 4096
    const int C  = N_EMBD;      // 1024
    const int N1 = 3 * C;       // 3072

    char* ws = (char*)d_ws;
    ushort* xb     = (ushort*)ws; ws += (size_t)M  * C * 2;
    ushort* wqkvT  = (ushort*)ws; ws += (size_t)N1 * C * 2;
    ushort* wprojT = (ushort*)ws; ws += (size_t)C  * C * 2;
    ushort* qkvb   = (ushort*)ws; ws += (size_t)M  * N1 * 2;
    ushort* yb     = (ushort*)ws; ws += (size_t)M  * C * 2;

    // 1. fused prep
    k_prep<<<8192, 256, 0, stream>>>(x, xb, Wqkv, wqkvT, Wproj, wprojT);
    // 2. qkv = x @ Wqkv + bqkv — 256x256 triple-buffered (grid 192, 1 blk/CU)
    {
        int nwg = (M / 256) * (N1 / 256);
        k_gemm1<true><<<nwg, 512, 0, stream>>>(xb, wqkvT, bqkv, (void*)qkvb, M, N1, C);
    }
    // 3. banded attention (XCD-chunked swizzle for K/V window L2 reuse)
    k_attn<<<BB * N_HEAD * (TT / 64), 256, 0, stream>>>(qkvb, yb);
    // 4. out = y @ Wproj + bproj — 128x64 256-thr (grid 512, ~3 blocks/CU)
    {
        int nwg = (M / 128) * (C / 64);
        k_gemm2<false><<<nwg, 256, 0, stream>>>(yb, wprojT, bproj, (void*)out, M, C, C);
    }
}

// Round 4
// 71.827 us; speedup vs baseline: 1.1116x; 1.1116x over previous
//
#include <hip/hip_runtime.h>
#include <hip/hip_bf16.h>
#include <math.h>

#define N_HEAD 16
#define N_EMBD 1024
#define HEADD  64
#define BANDW  64          // keys j in [i-64, i] visible
#define BB     2
#define TT     2048

typedef __attribute__((ext_vector_type(8))) short bf16x8;
typedef __attribute__((ext_vector_type(4))) float f32x4;

__device__ __forceinline__ ushort f2b(float f) {
    __hip_bfloat16 h = __float2bfloat16(f);
    union { __hip_bfloat16 h; ushort u; } cv; cv.h = h; return cv.u;
}
__device__ __forceinline__ float b2f(ushort u) { return __uint_as_float(((unsigned)u) << 16); }

// async global->LDS, 16B per lane; LDS dest = wave-uniform base (+lane*16 implicit)
#define GLOAD16(gp, lp) \
    __builtin_amdgcn_global_load_lds((const __attribute__((address_space(1))) void*)(gp), \
                                     (__attribute__((address_space(3))) void*)(lp), 16, 0, 0)

// ---------------- fused prep: x->bf16 + both weight transposes ----------------
__global__ __launch_bounds__(256) void k_prep(
    const float* __restrict__ x, ushort* __restrict__ xb,
    const float* __restrict__ Wqkv, ushort* __restrict__ wqkvT,
    const float* __restrict__ Wproj, ushort* __restrict__ wprojT)
{
    __shared__ float tile[32][33];
    int bid = blockIdx.x;
    int t = threadIdx.x;
    if (bid < 4096) {                       // x -> bf16 (4M floats, float4/thread)
        int i = bid * 256 + t;
        float4 v = reinterpret_cast<const float4*>(x)[i];
        ushort4 o;
        o.x = f2b(v.x); o.y = f2b(v.y); o.z = f2b(v.z); o.w = f2b(v.w);
        reinterpret_cast<ushort4*>(xb)[i] = o;
        return;
    }
    const float* in; ushort* out; int R, C, bx, by;
    if (bid < 4096 + 3072) {                // Wqkv [1024][3072] -> [3072][1024]
        int b2 = bid - 4096;
        in = Wqkv; out = wqkvT; R = 1024; C = 3072;
        bx = b2 % 96; by = b2 / 96;
    } else {                                // Wproj [1024][1024] -> transposed
        int b3 = bid - 7168;
        in = Wproj; out = wprojT; R = 1024; C = 1024;
        bx = b3 & 31; by = b3 >> 5;
    }
    int tx = t & 31, ty = t >> 5;
    int c0 = bx * 32, r0 = by * 32;
    for (int rr = ty; rr < 32; rr += 8)
        tile[rr][tx] = in[(size_t)(r0 + rr) * C + (c0 + tx)];
    __syncthreads();
    for (int cc = ty; cc < 32; cc += 8)
        out[(size_t)(c0 + cc) * R + (r0 + tx)] = f2b(tile[tx][cc]);
}

// ===== GEMM1: 256x192 tile, BK=64, split-ring counted-vmcnt schedule =====
// Grid 16x16 = 256 blocks = exactly 1/CU (round-3 fix: no idle CUs).
// A ring: 3 x 32 KB (triple), B ring: 2 x 24 KB (double) = 144 KB LDS.
// Per K-tile t: 4 phases x {7 ds_read, stage issues, barrier, lgkm0, 12 MFMA,
// barrier}. Stages: B(t+1) in ph0-2, A(t+2) in ph2-3; ONE counted wait
// vmcnt(4) at ph3 (confirms A(t+1)+B(t+1), leaves A(t+2) in flight).
// 8 waves 2Mx4N, wave output 128x48, acc[8][3] = 96 VGPR.
template <bool OUT_BF16>
__global__ __launch_bounds__(512, 2) void k_gemm1(
    const ushort* __restrict__ A, const ushort* __restrict__ BT,
    const float* __restrict__ bias, void* __restrict__ Cout,
    int M, int N, int K)
{
    __shared__ __align__(16) char lds[3 * 32768 + 2 * 24576];   // 144 KB
    const int K2 = K * 2;
    int tid = threadIdx.x, lane = tid & 63, w = tid >> 6;
    int wm = w >> 2, wn = w & 3;          // 2M x 4N
    int lr = lane & 15, kg = lane >> 4;

    int nbx = N / 192;                    // 16
    int cpx = gridDim.x >> 3;
    int wg = blockIdx.x;
    int wgid = (wg & 7) * cpx + (wg >> 3);
    int bx = wgid % nbx, by = wgid / nbx;
    int row0 = by * 256, col0 = bx * 192;

    // staging source offsets: round u covers LDS bytes [u*8192, u*8192+8192)
    // dest row r = o>>7 (128B rows), rotated source 16B-block c = ((o>>4)-r)&7
    size_t sA[4], sB[3];
#pragma unroll
    for (int u = 0; u < 4; ++u) {
        int o = u * 8192 + w * 1024 + lane * 16;
        int r = o >> 7, c = ((o >> 4) - r) & 7;
        sA[u] = (size_t)r * K2 + (size_t)c * 16;
    }
#pragma unroll
    for (int u = 0; u < 3; ++u) {
        int o = u * 8192 + w * 1024 + lane * 16;
        int r = o >> 7, c = ((o >> 4) - r) & 7;
        sB[u] = (size_t)r * K2 + (size_t)c * 16;
    }
    const char* gA = (const char*)A  + (size_t)row0 * K2;
    const char* gB = (const char*)BT + (size_t)col0 * K2;

    int offA[8][2], offB[3][2];
#pragma unroll
    for (int m = 0; m < 8; ++m) {
        int rr = wm * 128 + m * 16 + lr;          // 0..255
#pragma unroll
        for (int ks = 0; ks < 2; ++ks)
            offA[m][ks] = rr * 128 + (((ks * 4 + kg) + rr) & 7) * 16;
    }
#pragma unroll
    for (int n = 0; n < 3; ++n) {
        int rr = wn * 48 + n * 16 + lr;           // 0..191
#pragma unroll
        for (int ks = 0; ks < 2; ++ks)
            offB[n][ks] = rr * 128 + (((ks * 4 + kg) + rr) & 7) * 16;
    }

    f32x4 acc[8][3];
#pragma unroll
    for (int i = 0; i < 8; ++i)
#pragma unroll
        for (int j = 0; j < 3; ++j) { f32x4 z = {0.f, 0.f, 0.f, 0.f}; acc[i][j] = z; }

#define STG_A(SL, TI, RND) \
    GLOAD16(gA + (size_t)(TI) * 128 + sA[RND], \
            lds + (SL) * 32768 + (RND) * 8192 + w * 1024)
#define STG_B(SL, TI, RND) \
    GLOAD16(gB + (size_t)(TI) * 128 + sB[RND], \
            lds + 98304 + (SL) * 24576 + (RND) * 8192 + w * 1024)

    int nt = K >> 6;                      // 16 K-tiles of 64
    // prologue: A0,B0,A1,B1 (14 rounds); confirm tile 0 (leave A1+B1 = 7)
    STG_A(0, 0, 0); STG_A(0, 0, 1); STG_A(0, 0, 2); STG_A(0, 0, 3);
    STG_B(0, 0, 0); STG_B(0, 0, 1); STG_B(0, 0, 2);
    STG_A(1, 1, 0); STG_A(1, 1, 1); STG_A(1, 1, 2); STG_A(1, 1, 3);
    STG_B(1, 1, 0); STG_B(1, 1, 1); STG_B(1, 1, 2);
    asm volatile("s_waitcnt vmcnt(7)" ::: "memory");
    __builtin_amdgcn_s_barrier();

    int sa = 0;                           // A slot of current tile (t % 3)
    for (int t = 0; t < nt; ++t) {
        const char* bufA = lds + sa * 32768;
        const char* bufB = lds + 98304 + (t & 1) * 24576;
        int s2 = sa - 1; if (s2 < 0) s2 = 2;          // (t+2) % 3
        bool stB = (t >= 1) && (t + 1 < nt);          // stage B(t+1)
        bool stA = (t >= 1) && (t + 2 < nt);          // stage A(t+2)
        bool stA2 = (t == 0) && (nt > 2);             // t=0: stage A(2)
        bf16x8 b[3];
#pragma unroll
        for (int ph = 0; ph < 4; ++ph) {
            const int ks = ph >> 1, mh = ph & 1;
            // ---- ds_reads for THIS phase's MFMA quadrant ----
            bf16x8 a[4];
#pragma unroll
            for (int i = 0; i < 4; ++i)
                a[i] = *(const bf16x8*)(bufA + offA[mh * 4 + i][ks]);
            if (mh == 0) {
#pragma unroll
                for (int n = 0; n < 3; ++n)
                    b[n] = *(const bf16x8*)(bufB + offB[n][ks]);
            }
            // ---- stage issues for this phase ----
            if (ph == 0) {
                if (stB) STG_B((t + 1) & 1, t + 1, 0);
                if (stA2) STG_A(2, 2, 0);
            } else if (ph == 1) {
                if (stB) STG_B((t + 1) & 1, t + 1, 1);
                if (stA2) STG_A(2, 2, 1);
            } else if (ph == 2) {
                if (stB) STG_B((t + 1) & 1, t + 1, 2);
                if (stA) STG_A(s2, t + 2, 0);
                if (stA2) STG_A(2, 2, 2);
            } else {
                if (stA) { STG_A(s2, t + 2, 1); STG_A(s2, t + 2, 2); STG_A(s2, t + 2, 3); }
                if (stA2) STG_A(2, 2, 3);
                // end-of-tile counted wait: confirm tile t+1, keep A(t+2) in flight
                if (t + 2 < nt)
                    asm volatile("s_waitcnt vmcnt(4)" ::: "memory");
                else
                    asm volatile("s_waitcnt vmcnt(0)" ::: "memory");
            }
            __builtin_amdgcn_s_barrier();
            asm volatile("s_waitcnt lgkmcnt(0)" ::: "memory");
            __builtin_amdgcn_sched_barrier(0);
            __builtin_amdgcn_s_setprio(1);
#pragma unroll
            for (int i = 0; i < 4; ++i)
#pragma unroll
                for (int n = 0; n < 3; ++n)
                    acc[mh * 4 + i][n] = __builtin_amdgcn_mfma_f32_16x16x32_bf16(
                        a[i], b[n], acc[mh * 4 + i][n], 0, 0, 0);
            __builtin_amdgcn_s_setprio(0);
            __builtin_amdgcn_s_barrier();
        }
        sa = (sa == 2) ? 0 : sa + 1;
    }
#undef STG_A
#undef STG_B

#pragma unroll
    for (int m = 0; m < 8; ++m) {
        int growb = row0 + wm * 128 + m * 16 + kg * 4;
#pragma unroll
        for (int n = 0; n < 3; ++n) {
            int gcol = col0 + wn * 48 + n * 16 + lr;
            float bv = bias ? bias[gcol] : 0.f;
#pragma unroll
            for (int e = 0; e < 4; ++e) {
                float val = acc[m][n][e] + bv;
                if (OUT_BF16)
                    ((ushort*)Cout)[(size_t)(growb + e) * N + gcol] = f2b(val);
                else
                    ((float*)Cout)[(size_t)(growb + e) * N + gcol] = val;
            }
        }
    }
}

// ====== 128x64 2-phase dbuf GEMM (GEMM2), 256 thr / 4 waves, 3 blocks/CU ======
template <bool OUT_BF16>
__global__ __launch_bounds__(256, 3) void k_gemm2(
    const ushort* __restrict__ A, const ushort* __restrict__ BT,
    const float* __restrict__ bias, void* __restrict__ Cout,
    int M, int N, int K)
{
    __shared__ __align__(16) char lds[2 * 24576];
    const int K2 = K * 2;
    int t = threadIdx.x, lane = t & 63, w = t >> 6;   // 4 waves
    int wm = w >> 1, wn = w & 1;                      // 2M x 2N wave grid
    int lr = lane & 15, kg = lane >> 4;

    int nbx = N >> 6;                                 // tiles of 64 cols
    int cpx = gridDim.x >> 3;
    int wg = blockIdx.x;
    int wgid = (wg & 7) * cpx + (wg >> 3);
    int bx = wgid % nbx, by = wgid / nbx;
    int row0 = by * 128, col0 = bx * 64;

    size_t sA[4], sB[2];
#pragma unroll
    for (int u = 0; u < 4; ++u) {
        int o = w * 4096 + u * 1024 + lane * 16;
        int r = o >> 7, c = ((o >> 4) - r) & 7;
        sA[u] = (size_t)r * K2 + c * 16;
    }
#pragma unroll
    for (int u = 0; u < 2; ++u) {
        int o = w * 2048 + u * 1024 + lane * 16;
        int r = o >> 7, c = ((o >> 4) - r) & 7;
        sB[u] = (size_t)r * K2 + c * 16;
    }
    const char* gA = (const char*)A  + (size_t)row0 * K2;
    const char* gB = (const char*)BT + (size_t)col0 * K2;

    int offA[4][2], offB[2][2];
#pragma unroll
    for (int m = 0; m < 4; ++m) {
        int rr = wm * 64 + m * 16 + lr;
#pragma unroll
        for (int ks = 0; ks < 2; ++ks)
            offA[m][ks] = rr * 128 + (((ks * 4 + kg) + rr) & 7) * 16;
    }
#pragma unroll
    for (int n = 0; n < 2; ++n) {
        int rr = wn * 32 + n * 16 + lr;
#pragma unroll
        for (int ks = 0; ks < 2; ++ks)
            offB[n][ks] = rr * 128 + (((ks * 4 + kg) + rr) & 7) * 16;
    }

    f32x4 acc[4][2];
#pragma unroll
    for (int i = 0; i < 4; ++i)
#pragma unroll
        for (int j = 0; j < 2; ++j) { f32x4 z = {0.f, 0.f, 0.f, 0.f}; acc[i][j] = z; }

#define STAGE2(BUF, TI) do { \
        char* _db = lds + (BUF) * 24576; \
        const char* _ga = gA + (size_t)(TI) * 128; \
        const char* _gb = gB + (size_t)(TI) * 128; \
        GLOAD16(_ga + sA[0], _db + w * 4096); \
        GLOAD16(_ga + sA[1], _db + w * 4096 + 1024); \
        GLOAD16(_ga + sA[2], _db + w * 4096 + 2048); \
        GLOAD16(_ga + sA[3], _db + w * 4096 + 3072); \
        GLOAD16(_gb + sB[0], _db + 16384 + w * 2048); \
        GLOAD16(_gb + sB[1], _db + 16384 + w * 2048 + 1024); \
    } while (0)

    STAGE2(0, 0);
    __syncthreads();

    int nt = K >> 6;
#pragma unroll 2
    for (int tt = 0; tt < nt; ++tt) {
        int cur = tt & 1;
        if (tt + 1 < nt) STAGE2(cur ^ 1, tt + 1);
        const char* bufb = lds + cur * 24576;
#pragma unroll
        for (int ks = 0; ks < 2; ++ks) {
            bf16x8 af[4], bfr[2];
#pragma unroll
            for (int m = 0; m < 4; ++m)
                af[m] = *(const bf16x8*)(bufb + offA[m][ks]);
#pragma unroll
            for (int n = 0; n < 2; ++n)
                bfr[n] = *(const bf16x8*)(bufb + 16384 + offB[n][ks]);
#pragma unroll
            for (int m = 0; m < 4; ++m)
#pragma unroll
                for (int n = 0; n < 2; ++n)
                    acc[m][n] = __builtin_amdgcn_mfma_f32_16x16x32_bf16(
                        af[m], bfr[n], acc[m][n], 0, 0, 0);
        }
        __syncthreads();
    }
#undef STAGE2

#pragma unroll
    for (int m = 0; m < 4; ++m) {
        int growb = row0 + wm * 64 + m * 16 + kg * 4;
#pragma unroll
        for (int n = 0; n < 2; ++n) {
            int gcol = col0 + wn * 32 + n * 16 + lr;
            float bv = bias ? bias[gcol] : 0.f;
#pragma unroll
            for (int e = 0; e < 4; ++e) {
                float val = acc[m][n][e] + bv;
                if (OUT_BF16)
                    ((ushort*)Cout)[(size_t)(growb + e) * N + gcol] = f2b(val);
                else
                    ((float*)Cout)[(size_t)(growb + e) * N + gcol] = val;
            }
        }
    }
}

// ---------------- banded causal attention, MFMA block-tiled ----------------
__global__ __launch_bounds__(256) void k_attn(const ushort* __restrict__ qkv,
                                              ushort* __restrict__ y) {
    __shared__ __align__(16) ushort Ks[128 * 64];   // 16 KB, rotated layout
    __shared__ ushort Vt[64][136];                  // [d][key]
    __shared__ ushort Ps[64][136];                  // [query][key]

    const int R3 = 3 * N_EMBD;
    int bid = blockIdx.x;
    int l  = (bid & 7) * 128 + (bid >> 3);   // bijective: grid 1024 = 8*128
    int qt = l & 31;
    int h  = (l >> 5) & (N_HEAD - 1);
    int b  = l >> 9;
    int i0 = qt * 64;
    int j0 = i0 - BANDW;
    int hc = h * HEADD;

    int t    = threadIdx.x;
    int lane = t & 63;
    int wq   = t >> 6;
    int lr   = lane & 15;
    int kg   = lane >> 4;

    // ---- K: async global_load_lds, rotated dest (each wave 4 KB) ----
    const ushort* kbase_g = qkv + (size_t)b * TT * R3 + N_EMBD + hc;
#pragma unroll
    for (int rnd = 0; rnd < 4; ++rnd) {
        int o = wq * 4096 + rnd * 1024 + lane * 16;  // byte offset in Ks
        int row  = o >> 7;
        int cblk = (((o >> 4) & 7) - row) & 7;       // inverse rotation
        int j = j0 + row; if (j < 0) j = 0;          // clamp; masked later
        GLOAD16((const char*)(kbase_g + (size_t)j * R3) + cblk * 16,
                (char*)Ks + wq * 4096 + rnd * 1024);
    }

    // ---- V: register staging + scalar transpose (round-8 proven) ----
    {
        int row  = t >> 1;            // 0..127 (key index in window)
        int part = t & 1;             // halves of the 64-wide d
        int j = j0 + row;
        if (j >= 0) {
            const ushort* vrow = qkv + (size_t)(b * TT + j) * R3 + 2 * N_EMBD + hc + part * 32;
#pragma unroll
            for (int c = 0; c < 4; ++c) {
                uint4 vv = reinterpret_cast<const uint4*>(vrow)[c];
                const ushort* pv = (const ushort*)&vv;
                int dbase = part * 32 + c * 8;
#pragma unroll
                for (int e = 0; e < 8; ++e)
                    Vt[dbase + e][row] = pv[e];
            }
        } else {
#pragma unroll
            for (int c = 0; c < 4; ++c) {
                int dbase = part * 32 + c * 8;
#pragma unroll
                for (int e = 0; e < 8; ++e)
                    Vt[dbase + e][row] = 0;
            }
        }
    }

    // ---- Q fragments direct from global ----
    const ushort* qbase = qkv + (size_t)(b * TT + i0 + wq * 16 + lr) * R3 + hc;
    bf16x8 aq0 = *reinterpret_cast<const bf16x8*>(qbase + kg * 8);
    bf16x8 aq1 = *reinterpret_cast<const bf16x8*>(qbase + 32 + kg * 8);

    __syncthreads();

    // ---- QK^T (rotated K reads; 2 lanes/slot per quarter-wave = conflict-free) ----
    f32x4 s[8];
#pragma unroll
    for (int nt = 0; nt < 8; ++nt) { f32x4 z = {0.f, 0.f, 0.f, 0.f}; s[nt] = z; }
#pragma unroll
    for (int nt = 0; nt < 8; ++nt) {
        int row = nt * 16 + lr;
        const char* kr = (const char*)Ks + row * 128;
        bf16x8 kb0 = *(const bf16x8*)(kr + (((kg)     + row) & 7) * 16);
        bf16x8 kb1 = *(const bf16x8*)(kr + (((4 + kg) + row) & 7) * 16);
        s[nt] = __builtin_amdgcn_mfma_f32_16x16x32_bf16(aq0, kb0, s[nt], 0, 0, 0);
        s[nt] = __builtin_amdgcn_mfma_f32_16x16x32_bf16(aq1, kb1, s[nt], 0, 0, 0);
    }

    // ---- mask + softmax (rows in (kg,e); reduce over lr via shfl_xor) ----
    float mx[4] = {-INFINITY, -INFINITY, -INFINITY, -INFINITY};
#pragma unroll
    for (int nt = 0; nt < 8; ++nt) {
        int kc = nt * 16 + lr;
#pragma unroll
        for (int e = 0; e < 4; ++e) {
            int qr = wq * 16 + kg * 4 + e;
            bool valid = (kc >= qr) && (kc <= qr + BANDW) && (j0 + kc >= 0);
            float v = s[nt][e] * 0.125f;
            s[nt][e] = valid ? v : -INFINITY;
            mx[e] = fmaxf(mx[e], s[nt][e]);
        }
    }
#pragma unroll
    for (int e = 0; e < 4; ++e) {
#pragma unroll
        for (int m = 1; m <= 8; m <<= 1)
            mx[e] = fmaxf(mx[e], __shfl_xor(mx[e], m, 64));
    }
    float sm[4] = {0.f, 0.f, 0.f, 0.f};
#pragma unroll
    for (int nt = 0; nt < 8; ++nt) {
        int kc = nt * 16 + lr;
#pragma unroll
        for (int e = 0; e < 4; ++e) {
            float p = __expf(s[nt][e] - mx[e]);
            sm[e] += p;
            Ps[wq * 16 + kg * 4 + e][kc] = f2b(p);
        }
    }
#pragma unroll
    for (int e = 0; e < 4; ++e) {
#pragma unroll
        for (int m = 1; m <= 8; m <<= 1)
            sm[e] += __shfl_xor(sm[e], m, 64);
    }
    // no barrier: each wave reads only its own Ps rows

    // ---- PV: y(16x64) = P(16x128) @ V(128x64), Vt is [d][key] ----
    f32x4 o[4];
#pragma unroll
    for (int vt = 0; vt < 4; ++vt) { f32x4 z = {0.f, 0.f, 0.f, 0.f}; o[vt] = z; }
#pragma unroll
    for (int ks = 0; ks < 4; ++ks) {
        bf16x8 pa = *reinterpret_cast<const bf16x8*>(&Ps[wq * 16 + lr][ks * 32 + kg * 8]);
#pragma unroll
        for (int vt = 0; vt < 4; ++vt) {
            bf16x8 vb = *reinterpret_cast<const bf16x8*>(&Vt[vt * 16 + lr][ks * 32 + kg * 8]);
            o[vt] = __builtin_amdgcn_mfma_f32_16x16x32_bf16(pa, vb, o[vt], 0, 0, 0);
        }
    }

    float inv[4];
#pragma unroll
    for (int e = 0; e < 4; ++e) inv[e] = 1.f / sm[e];

#pragma unroll
    for (int vt = 0; vt < 4; ++vt) {
#pragma unroll
        for (int e = 0; e < 4; ++e) {
            int qr = wq * 16 + kg * 4 + e;
            y[(size_t)(b * TT + i0 + qr) * N_EMBD + hc + vt * 16 + lr] =
                f2b(o[vt][e] * inv[e]);
        }
    }
}

// ---------------- launch ----------------
extern "C" void kernel_launch(void* const* d_in, const int* in_sizes, int n_in,
                              void* d_out, int out_size, void* d_ws, size_t ws_size,
                              hipStream_t stream) {
    const float* x     = (const float*)d_in[0];
    const float* Wqkv  = (const float*)d_in[1];
    const float* bqkv  = (const float*)d_in[2];
    const float* Wproj = (const float*)d_in[3];
    const float* bproj = (const float*)d_in[4];
    float* out = (float*)d_out;

    const int M  = BB * TT;     // 4096
    const int C  = N_EMBD;      // 1024
    const int N1 = 3 * C;       // 3072

    char* ws = (char*)d_ws;
    ushort* xb     = (ushort*)ws; ws += (size_t)M  * C * 2;
    ushort* wqkvT  = (ushort*)ws; ws += (size_t)N1 * C * 2;
    ushort* wprojT = (ushort*)ws; ws += (size_t)C  * C * 2;
    ushort* qkvb   = (ushort*)ws; ws += (size_t)M  * N1 * 2;
    ushort* yb     = (ushort*)ws; ws += (size_t)M  * C * 2;

    // 1. fused prep
    k_prep<<<8192, 256, 0, stream>>>(x, xb, Wqkv, wqkvT, Wproj, wprojT);
    // 2. qkv = x @ Wqkv + bqkv — 256x192 split-ring (grid 256 = 1 blk/CU exact)
    {
        int nwg = (M / 256) * (N1 / 192);
        k_gemm1<true><<<nwg, 512, 0, stream>>>(xb, wqkvT, bqkv, (void*)qkvb, M, N1, C);
    }
    // 3. banded attention (XCD-chunked swizzle for K/V window L2 reuse)
    k_attn<<<BB * N_HEAD * (TT / 64), 256, 0, stream>>>(qkvb, yb);
    // 4. out = y @ Wproj + bproj — 128x64 256-thr (grid 512, ~3 blocks/CU)
    {
        int nwg = (M / 128) * (C / 64);
        k_gemm2<false><<<nwg, 256, 0, stream>>>(yb, wprojT, bproj, (void*)out, M, C, C);
    }
}

// Round 5
// 68.540 us; speedup vs baseline: 1.1649x; 1.0480x over previous
//
#include <hip/hip_runtime.h>
#include <hip/hip_bf16.h>
#include <math.h>

#define N_HEAD 16
#define N_EMBD 1024
#define HEADD  64
#define BANDW  64          // keys j in [i-64, i] visible
#define BB     2
#define TT     2048

typedef __attribute__((ext_vector_type(8))) short bf16x8;
typedef __attribute__((ext_vector_type(4))) float f32x4;

__device__ __forceinline__ ushort f2b(float f) {
    __hip_bfloat16 h = __float2bfloat16(f);
    union { __hip_bfloat16 h; ushort u; } cv; cv.h = h; return cv.u;
}
__device__ __forceinline__ float b2f(ushort u) { return __uint_as_float(((unsigned)u) << 16); }

// async global->LDS, 16B per lane; LDS dest = wave-uniform base (+lane*16 implicit)
#define GLOAD16(gp, lp) \
    __builtin_amdgcn_global_load_lds((const __attribute__((address_space(1))) void*)(gp), \
                                     (__attribute__((address_space(3))) void*)(lp), 16, 0, 0)

// ---------------- fused prep: x->bf16 + both weight transposes ----------------
__global__ __launch_bounds__(256) void k_prep(
    const float* __restrict__ x, ushort* __restrict__ xb,
    const float* __restrict__ Wqkv, ushort* __restrict__ wqkvT,
    const float* __restrict__ Wproj, ushort* __restrict__ wprojT)
{
    __shared__ float tile[32][33];
    int bid = blockIdx.x;
    int t = threadIdx.x;
    if (bid < 4096) {                       // x -> bf16 (4M floats, float4/thread)
        int i = bid * 256 + t;
        float4 v = reinterpret_cast<const float4*>(x)[i];
        ushort4 o;
        o.x = f2b(v.x); o.y = f2b(v.y); o.z = f2b(v.z); o.w = f2b(v.w);
        reinterpret_cast<ushort4*>(xb)[i] = o;
        return;
    }
    const float* in; ushort* out; int R, C, bx, by;
    if (bid < 4096 + 3072) {                // Wqkv [1024][3072] -> [3072][1024]
        int b2 = bid - 4096;
        in = Wqkv; out = wqkvT; R = 1024; C = 3072;
        bx = b2 % 96; by = b2 / 96;
    } else {                                // Wproj [1024][1024] -> transposed
        int b3 = bid - 7168;
        in = Wproj; out = wprojT; R = 1024; C = 1024;
        bx = b3 & 31; by = b3 >> 5;
    }
    int tx = t & 31, ty = t >> 5;
    int c0 = bx * 32, r0 = by * 32;
    for (int rr = ty; rr < 32; rr += 8)
        tile[rr][tx] = in[(size_t)(r0 + rr) * C + (c0 + tx)];
    __syncthreads();
    for (int cc = ty; cc < 32; cc += 8)
        out[(size_t)(c0 + cc) * R + (r0 + tx)] = f2b(tile[tx][cc]);
}

// ===== GEMM1: 128x192 dbuf, COUNTED-vmcnt self-overwrite schedule =====
// Proven tile/offsets/2-blk-CU/2-barriers-per-K-tile; the only change vs the
// 69.7us baseline: all 14 frags -> regs, lgkm0+barrier frees buf(cur), stage
// tile t+2 INTO buf(cur), MFMA cluster hides the wait, counted vmcnt(5)
// (confirms tile t+1, leaves t+2 in flight) - never drains to 0 mid-loop.
template <bool OUT_BF16>
__global__ __launch_bounds__(512, 4) void k_gemm1(
    const ushort* __restrict__ A, const ushort* __restrict__ BT,
    const float* __restrict__ bias, void* __restrict__ Cout,
    int M, int N, int K)
{
    __shared__ __align__(16) char lds[81920];
    const int K2 = K * 2;
    int t = threadIdx.x, lane = t & 63, w = t >> 6;
    int wm = w >> 2, wn = w & 3;
    int lr = lane & 15, kg = lane >> 4;

    int nbx = N / 192;
    int cpx = gridDim.x >> 3;
    int wg = blockIdx.x;
    int wgid = (wg & 7) * cpx + (wg >> 3);
    int bx = wgid % nbx, by = wgid / nbx;
    int row0 = by * 128, col0 = bx * 192;

    size_t sA0, sA1, sB0, sB1, sB2;
    {
        int o = w * 2048 + lane * 16;
        int r = o >> 7, c = ((o >> 4) - r) & 7;
        sA0 = (size_t)r * K2 + c * 16;
        o += 1024; r = o >> 7; c = ((o >> 4) - r) & 7;
        sA1 = (size_t)r * K2 + c * 16;
        int ob = w * 3072 + lane * 16;
        int rb = ob >> 7, cb = ((ob >> 4) - rb) & 7;
        sB0 = (size_t)rb * K2 + cb * 16;
        ob += 1024; rb = ob >> 7; cb = ((ob >> 4) - rb) & 7;
        sB1 = (size_t)rb * K2 + cb * 16;
        ob += 1024; rb = ob >> 7; cb = ((ob >> 4) - rb) & 7;
        sB2 = (size_t)rb * K2 + cb * 16;
    }
    const char* gA = (const char*)A  + (size_t)row0 * K2;
    const char* gB = (const char*)BT + (size_t)col0 * K2;

    int offA[4][2], offB[3][2];
#pragma unroll
    for (int m = 0; m < 4; ++m) {
        int rr = wm * 64 + m * 16 + lr;
#pragma unroll
        for (int ks = 0; ks < 2; ++ks)
            offA[m][ks] = rr * 128 + (((ks * 4 + kg) + rr) & 7) * 16;
    }
#pragma unroll
    for (int n = 0; n < 3; ++n) {
        int rr = wn * 48 + n * 16 + lr;
#pragma unroll
        for (int ks = 0; ks < 2; ++ks)
            offB[n][ks] = rr * 128 + (((ks * 4 + kg) + rr) & 7) * 16;
    }

    f32x4 acc[4][3];
#pragma unroll
    for (int i = 0; i < 4; ++i)
#pragma unroll
        for (int j = 0; j < 3; ++j) { f32x4 z = {0.f, 0.f, 0.f, 0.f}; acc[i][j] = z; }

#define STAGE1(BUF, TI) do { \
        char* _db = lds + (BUF) * 40960; \
        const char* _ga = gA + (size_t)(TI) * 128; \
        const char* _gb = gB + (size_t)(TI) * 128; \
        GLOAD16(_ga + sA0, _db + w * 2048); \
        GLOAD16(_ga + sA1, _db + w * 2048 + 1024); \
        GLOAD16(_gb + sB0, _db + 16384 + w * 3072); \
        GLOAD16(_gb + sB1, _db + 16384 + w * 3072 + 1024); \
        GLOAD16(_gb + sB2, _db + 16384 + w * 3072 + 2048); \
    } while (0)

    int nt = K >> 6;                 // 16
    STAGE1(0, 0);
    STAGE1(1, 1);
    asm volatile("s_waitcnt vmcnt(5)" ::: "memory");   // confirm tile 0
    __builtin_amdgcn_s_barrier();

#pragma unroll 2
    for (int tt = 0; tt < nt; ++tt) {
        int cur = tt & 1;
        const char* bufb = lds + cur * 40960;
        // ---- all 14 frags of buf(cur) into regs ----
        bf16x8 af[4][2], bfr[3][2];
#pragma unroll
        for (int ks = 0; ks < 2; ++ks) {
#pragma unroll
            for (int m = 0; m < 4; ++m)
                af[m][ks] = *(const bf16x8*)(bufb + offA[m][ks]);
#pragma unroll
            for (int n = 0; n < 3; ++n)
                bfr[n][ks] = *(const bf16x8*)(bufb + 16384 + offB[n][ks]);
        }
        asm volatile("s_waitcnt lgkmcnt(0)" ::: "memory");  // reads in regs
        __builtin_amdgcn_sched_barrier(0);
        __builtin_amdgcn_s_barrier();                       // buf(cur) free
        if (tt + 2 < nt) STAGE1(cur, tt + 2);               // overwrite buf(cur)
        // ---- MFMA on regs (hides stage issue + wait) ----
#pragma unroll
        for (int ks = 0; ks < 2; ++ks)
#pragma unroll
            for (int m = 0; m < 4; ++m)
#pragma unroll
                for (int n = 0; n < 3; ++n)
                    acc[m][n] = __builtin_amdgcn_mfma_f32_16x16x32_bf16(
                        af[m][ks], bfr[n][ks], acc[m][n], 0, 0, 0);
        if (tt + 2 < nt)
            asm volatile("s_waitcnt vmcnt(5)" ::: "memory"); // confirm tile tt+1
        else
            asm volatile("s_waitcnt vmcnt(0)" ::: "memory"); // tail drain
        __builtin_amdgcn_s_barrier();                        // tile tt+1 ready
    }
#undef STAGE1

#pragma unroll
    for (int m = 0; m < 4; ++m) {
        int growb = row0 + wm * 64 + m * 16 + kg * 4;
#pragma unroll
        for (int n = 0; n < 3; ++n) {
            int gcol = col0 + wn * 48 + n * 16 + lr;
            float bv = bias ? bias[gcol] : 0.f;
#pragma unroll
            for (int e = 0; e < 4; ++e) {
                float val = acc[m][n][e] + bv;
                if (OUT_BF16)
                    ((ushort*)Cout)[(size_t)(growb + e) * N + gcol] = f2b(val);
                else
                    ((float*)Cout)[(size_t)(growb + e) * N + gcol] = val;
            }
        }
    }
}

// ====== GEMM2: 128x64 dbuf, same counted-vmcnt self-overwrite schedule ======
template <bool OUT_BF16>
__global__ __launch_bounds__(256, 3) void k_gemm2(
    const ushort* __restrict__ A, const ushort* __restrict__ BT,
    const float* __restrict__ bias, void* __restrict__ Cout,
    int M, int N, int K)
{
    __shared__ __align__(16) char lds[2 * 24576];
    const int K2 = K * 2;
    int t = threadIdx.x, lane = t & 63, w = t >> 6;   // 4 waves
    int wm = w >> 1, wn = w & 1;                      // 2M x 2N wave grid
    int lr = lane & 15, kg = lane >> 4;

    int nbx = N >> 6;                                 // tiles of 64 cols
    int cpx = gridDim.x >> 3;
    int wg = blockIdx.x;
    int wgid = (wg & 7) * cpx + (wg >> 3);
    int bx = wgid % nbx, by = wgid / nbx;
    int row0 = by * 128, col0 = bx * 64;

    size_t sA[4], sB[2];
#pragma unroll
    for (int u = 0; u < 4; ++u) {
        int o = w * 4096 + u * 1024 + lane * 16;
        int r = o >> 7, c = ((o >> 4) - r) & 7;
        sA[u] = (size_t)r * K2 + c * 16;
    }
#pragma unroll
    for (int u = 0; u < 2; ++u) {
        int o = w * 2048 + u * 1024 + lane * 16;
        int r = o >> 7, c = ((o >> 4) - r) & 7;
        sB[u] = (size_t)r * K2 + c * 16;
    }
    const char* gA = (const char*)A  + (size_t)row0 * K2;
    const char* gB = (const char*)BT + (size_t)col0 * K2;

    int offA[4][2], offB[2][2];
#pragma unroll
    for (int m = 0; m < 4; ++m) {
        int rr = wm * 64 + m * 16 + lr;
#pragma unroll
        for (int ks = 0; ks < 2; ++ks)
            offA[m][ks] = rr * 128 + (((ks * 4 + kg) + rr) & 7) * 16;
    }
#pragma unroll
    for (int n = 0; n < 2; ++n) {
        int rr = wn * 32 + n * 16 + lr;
#pragma unroll
        for (int ks = 0; ks < 2; ++ks)
            offB[n][ks] = rr * 128 + (((ks * 4 + kg) + rr) & 7) * 16;
    }

    f32x4 acc[4][2];
#pragma unroll
    for (int i = 0; i < 4; ++i)
#pragma unroll
        for (int j = 0; j < 2; ++j) { f32x4 z = {0.f, 0.f, 0.f, 0.f}; acc[i][j] = z; }

#define STAGE2(BUF, TI) do { \
        char* _db = lds + (BUF) * 24576; \
        const char* _ga = gA + (size_t)(TI) * 128; \
        const char* _gb = gB + (size_t)(TI) * 128; \
        GLOAD16(_ga + sA[0], _db + w * 4096); \
        GLOAD16(_ga + sA[1], _db + w * 4096 + 1024); \
        GLOAD16(_ga + sA[2], _db + w * 4096 + 2048); \
        GLOAD16(_ga + sA[3], _db + w * 4096 + 3072); \
        GLOAD16(_gb + sB[0], _db + 16384 + w * 2048); \
        GLOAD16(_gb + sB[1], _db + 16384 + w * 2048 + 1024); \
    } while (0)

    int nt = K >> 6;                 // 16
    STAGE2(0, 0);
    STAGE2(1, 1);
    asm volatile("s_waitcnt vmcnt(6)" ::: "memory");   // confirm tile 0
    __builtin_amdgcn_s_barrier();

#pragma unroll 2
    for (int tt = 0; tt < nt; ++tt) {
        int cur = tt & 1;
        const char* bufb = lds + cur * 24576;
        bf16x8 af[4][2], bfr[2][2];
#pragma unroll
        for (int ks = 0; ks < 2; ++ks) {
#pragma unroll
            for (int m = 0; m < 4; ++m)
                af[m][ks] = *(const bf16x8*)(bufb + offA[m][ks]);
#pragma unroll
            for (int n = 0; n < 2; ++n)
                bfr[n][ks] = *(const bf16x8*)(bufb + 16384 + offB[n][ks]);
        }
        asm volatile("s_waitcnt lgkmcnt(0)" ::: "memory");
        __builtin_amdgcn_sched_barrier(0);
        __builtin_amdgcn_s_barrier();                       // buf(cur) free
        if (tt + 2 < nt) STAGE2(cur, tt + 2);
#pragma unroll
        for (int ks = 0; ks < 2; ++ks)
#pragma unroll
            for (int m = 0; m < 4; ++m)
#pragma unroll
                for (int n = 0; n < 2; ++n)
                    acc[m][n] = __builtin_amdgcn_mfma_f32_16x16x32_bf16(
                        af[m][ks], bfr[n][ks], acc[m][n], 0, 0, 0);
        if (tt + 2 < nt)
            asm volatile("s_waitcnt vmcnt(6)" ::: "memory");
        else
            asm volatile("s_waitcnt vmcnt(0)" ::: "memory");
        __builtin_amdgcn_s_barrier();
    }
#undef STAGE2

#pragma unroll
    for (int m = 0; m < 4; ++m) {
        int growb = row0 + wm * 64 + m * 16 + kg * 4;
#pragma unroll
        for (int n = 0; n < 2; ++n) {
            int gcol = col0 + wn * 32 + n * 16 + lr;
            float bv = bias ? bias[gcol] : 0.f;
#pragma unroll
            for (int e = 0; e < 4; ++e) {
                float val = acc[m][n][e] + bv;
                if (OUT_BF16)
                    ((ushort*)Cout)[(size_t)(growb + e) * N + gcol] = f2b(val);
                else
                    ((float*)Cout)[(size_t)(growb + e) * N + gcol] = val;
            }
        }
    }
}

// ---------------- banded causal attention, MFMA block-tiled ----------------
__global__ __launch_bounds__(256) void k_attn(const ushort* __restrict__ qkv,
                                              ushort* __restrict__ y) {
    __shared__ __align__(16) ushort Ks[128 * 64];   // 16 KB, rotated layout
    __shared__ ushort Vt[64][136];                  // [d][key]
    __shared__ ushort Ps[64][136];                  // [query][key]

    const int R3 = 3 * N_EMBD;
    int bid = blockIdx.x;
    int l  = (bid & 7) * 128 + (bid >> 3);   // bijective: grid 1024 = 8*128
    int qt = l & 31;
    int h  = (l >> 5) & (N_HEAD - 1);
    int b  = l >> 9;
    int i0 = qt * 64;
    int j0 = i0 - BANDW;
    int hc = h * HEADD;

    int t    = threadIdx.x;
    int lane = t & 63;
    int wq   = t >> 6;
    int lr   = lane & 15;
    int kg   = lane >> 4;

    // ---- K: async global_load_lds, rotated dest (each wave 4 KB) ----
    const ushort* kbase_g = qkv + (size_t)b * TT * R3 + N_EMBD + hc;
#pragma unroll
    for (int rnd = 0; rnd < 4; ++rnd) {
        int o = wq * 4096 + rnd * 1024 + lane * 16;  // byte offset in Ks
        int row  = o >> 7;
        int cblk = (((o >> 4) & 7) - row) & 7;       // inverse rotation
        int j = j0 + row; if (j < 0) j = 0;          // clamp; masked later
        GLOAD16((const char*)(kbase_g + (size_t)j * R3) + cblk * 16,
                (char*)Ks + wq * 4096 + rnd * 1024);
    }

    // ---- V: register staging + scalar transpose (round-8 proven) ----
    {
        int row  = t >> 1;            // 0..127 (key index in window)
        int part = t & 1;             // halves of the 64-wide d
        int j = j0 + row;
        if (j >= 0) {
            const ushort* vrow = qkv + (size_t)(b * TT + j) * R3 + 2 * N_EMBD + hc + part * 32;
#pragma unroll
            for (int c = 0; c < 4; ++c) {
                uint4 vv = reinterpret_cast<const uint4*>(vrow)[c];
                const ushort* pv = (const ushort*)&vv;
                int dbase = part * 32 + c * 8;
#pragma unroll
                for (int e = 0; e < 8; ++e)
                    Vt[dbase + e][row] = pv[e];
            }
        } else {
#pragma unroll
            for (int c = 0; c < 4; ++c) {
                int dbase = part * 32 + c * 8;
#pragma unroll
                for (int e = 0; e < 8; ++e)
                    Vt[dbase + e][row] = 0;
            }
        }
    }

    // ---- Q fragments direct from global ----
    const ushort* qbase = qkv + (size_t)(b * TT + i0 + wq * 16 + lr) * R3 + hc;
    bf16x8 aq0 = *reinterpret_cast<const bf16x8*>(qbase + kg * 8);
    bf16x8 aq1 = *reinterpret_cast<const bf16x8*>(qbase + 32 + kg * 8);

    __syncthreads();

    // ---- QK^T (rotated K reads; 2 lanes/slot per quarter-wave = conflict-free) ----
    f32x4 s[8];
#pragma unroll
    for (int nt = 0; nt < 8; ++nt) { f32x4 z = {0.f, 0.f, 0.f, 0.f}; s[nt] = z; }
#pragma unroll
    for (int nt = 0; nt < 8; ++nt) {
        int row = nt * 16 + lr;
        const char* kr = (const char*)Ks + row * 128;
        bf16x8 kb0 = *(const bf16x8*)(kr + (((kg)     + row) & 7) * 16);
        bf16x8 kb1 = *(const bf16x8*)(kr + (((4 + kg) + row) & 7) * 16);
        s[nt] = __builtin_amdgcn_mfma_f32_16x16x32_bf16(aq0, kb0, s[nt], 0, 0, 0);
        s[nt] = __builtin_amdgcn_mfma_f32_16x16x32_bf16(aq1, kb1, s[nt], 0, 0, 0);
    }

    // ---- mask + softmax (rows in (kg,e); reduce over lr via shfl_xor) ----
    float mx[4] = {-INFINITY, -INFINITY, -INFINITY, -INFINITY};
#pragma unroll
    for (int nt = 0; nt < 8; ++nt) {
        int kc = nt * 16 + lr;
#pragma unroll
        for (int e = 0; e < 4; ++e) {
            int qr = wq * 16 + kg * 4 + e;
            bool valid = (kc >= qr) && (kc <= qr + BANDW) && (j0 + kc >= 0);
            float v = s[nt][e] * 0.125f;
            s[nt][e] = valid ? v : -INFINITY;
            mx[e] = fmaxf(mx[e], s[nt][e]);
        }
    }
#pragma unroll
    for (int e = 0; e < 4; ++e) {
#pragma unroll
        for (int m = 1; m <= 8; m <<= 1)
            mx[e] = fmaxf(mx[e], __shfl_xor(mx[e], m, 64));
    }
    float sm[4] = {0.f, 0.f, 0.f, 0.f};
#pragma unroll
    for (int nt = 0; nt < 8; ++nt) {
        int kc = nt * 16 + lr;
#pragma unroll
        for (int e = 0; e < 4; ++e) {
            float p = __expf(s[nt][e] - mx[e]);
            sm[e] += p;
            Ps[wq * 16 + kg * 4 + e][kc] = f2b(p);
        }
    }
#pragma unroll
    for (int e = 0; e < 4; ++e) {
#pragma unroll
        for (int m = 1; m <= 8; m <<= 1)
            sm[e] += __shfl_xor(sm[e], m, 64);
    }
    // no barrier: each wave reads only its own Ps rows

    // ---- PV: y(16x64) = P(16x128) @ V(128x64), Vt is [d][key] ----
    f32x4 o[4];
#pragma unroll
    for (int vt = 0; vt < 4; ++vt) { f32x4 z = {0.f, 0.f, 0.f, 0.f}; o[vt] = z; }
#pragma unroll
    for (int ks = 0; ks < 4; ++ks) {
        bf16x8 pa = *reinterpret_cast<const bf16x8*>(&Ps[wq * 16 + lr][ks * 32 + kg * 8]);
#pragma unroll
        for (int vt = 0; vt < 4; ++vt) {
            bf16x8 vb = *reinterpret_cast<const bf16x8*>(&Vt[vt * 16 + lr][ks * 32 + kg * 8]);
            o[vt] = __builtin_amdgcn_mfma_f32_16x16x32_bf16(pa, vb, o[vt], 0, 0, 0);
        }
    }

    float inv[4];
#pragma unroll
    for (int e = 0; e < 4; ++e) inv[e] = 1.f / sm[e];

#pragma unroll
    for (int vt = 0; vt < 4; ++vt) {
#pragma unroll
        for (int e = 0; e < 4; ++e) {
            int qr = wq * 16 + kg * 4 + e;
            y[(size_t)(b * TT + i0 + qr) * N_EMBD + hc + vt * 16 + lr] =
                f2b(o[vt][e] * inv[e]);
        }
    }
}

// ---------------- launch ----------------
extern "C" void kernel_launch(void* const* d_in, const int* in_sizes, int n_in,
                              void* d_out, int out_size, void* d_ws, size_t ws_size,
                              hipStream_t stream) {
    const float* x     = (const float*)d_in[0];
    const float* Wqkv  = (const float*)d_in[1];
    const float* bqkv  = (const float*)d_in[2];
    const float* Wproj = (const float*)d_in[3];
    const float* bproj = (const float*)d_in[4];
    float* out = (float*)d_out;

    const int M  = BB * TT;     // 4096
    const int C  = N_EMBD;      // 1024
    const int N1 = 3 * C;       // 3072

    char* ws = (char*)d_ws;
    ushort* xb     = (ushort*)ws; ws += (size_t)M  * C * 2;
    ushort* wqkvT  = (ushort*)ws; ws += (size_t)N1 * C * 2;
    ushort* wprojT = (ushort*)ws; ws += (size_t)C  * C * 2;
    ushort* qkvb   = (ushort*)ws; ws += (size_t)M  * N1 * 2;
    ushort* yb     = (ushort*)ws; ws += (size_t)M  * C * 2;

    // 1. fused prep
    k_prep<<<8192, 256, 0, stream>>>(x, xb, Wqkv, wqkvT, Wproj, wprojT);
    // 2. qkv = x @ Wqkv + bqkv — 128x192 counted-vmcnt (grid 512, 2 blk/CU)
    {
        int nwg = (M / 128) * (N1 / 192);
        k_gemm1<true><<<nwg, 512, 0, stream>>>(xb, wqkvT, bqkv, (void*)qkvb, M, N1, C);
    }
    // 3. banded attention (XCD-chunked swizzle for K/V window L2 reuse)
    k_attn<<<BB * N_HEAD * (TT / 64), 256, 0, stream>>>(qkvb, yb);
    // 4. out = y @ Wproj + bproj — 128x64 counted-vmcnt (grid 512, 3 blk/CU)
    {
        int nwg = (M / 128) * (C / 64);
        k_gemm2<false><<<nwg, 256, 0, stream>>>(yb, wprojT, bproj, (void*)out, M, C, C);
    }
}